// Round 1
// baseline (649.645 us; speedup 1.0000x reference)
//
#include <hip/hip_runtime.h>

// ---------------------------------------------------------------------------
// EdgeUpdaterFrameDiff: x_down proj -> outer-concat edge bias -> 2-layer MLP
// with relu + residual -> out proj -> LayerNorm.  bf16 MFMA implementation.
//
// Inputs (f32): x[512,1,256], z[1,512,512,128], Wd[128,256], bd[128],
//   W1[384,384], b1[384], W2[384,384], b2[384], Wo[128,384], bo[128],
//   gamma[128], beta[128].  Output f32 [1,512,512,128].
// ---------------------------------------------------------------------------

using bf16x8 = __attribute__((ext_vector_type(8))) __bf16;
using f32x16 = __attribute__((ext_vector_type(16))) float;

#define LPAD 392            // bf16 row stride for 384-wide LDS tiles (16B aligned)
#define OPAD 132            // f32 row stride for 128-wide LN staging

__device__ inline unsigned short f2bf(float f) {
    union { float f; unsigned int u; } v; v.f = f;
    unsigned int r = v.u + 0x7fffu + ((v.u >> 16) & 1u);   // RNE
    return (unsigned short)(r >> 16);
}
__device__ inline float bf2f(unsigned short h) {
    union { unsigned int u; float f; } v; v.u = ((unsigned int)h) << 16;
    return v.f;
}

// ---------------- prep: x_down = x @ Wd^T + bd  (bf16 out) -----------------
// grid 64 x 128 threads; each block handles 8 rows of i.
__global__ void k_xdown(const float* __restrict__ x, const float* __restrict__ Wd,
                        const float* __restrict__ bd, unsigned short* __restrict__ xd) {
    __shared__ float sx[8 * 256];
    const int t = threadIdx.x;           // 0..127 -> output col n
    const int ibase = blockIdx.x * 8;
    for (int c = t; c < 8 * 256; c += 128) sx[c] = x[ibase * 256 + c];
    __syncthreads();
    const float bias = bd[t];
    const float* wr = &Wd[t * 256];
    for (int ii = 0; ii < 8; ++ii) {
        const float* xr = &sx[ii * 256];
        float sum = 0.f;
#pragma unroll 8
        for (int k = 0; k < 256; k += 4) {
            float4 wv = *(const float4*)&wr[k];
            float4 xv = *(const float4*)&xr[k];
            sum += wv.x * xv.x + wv.y * xv.y + wv.z * xv.z + wv.w * xv.w;
        }
        xd[(ibase + ii) * 128 + t] = f2bf(sum + bias);
    }
}

// ------------- prep: swizzle weights into MFMA B-fragment order ------------
// dst chunk c = (nt*24 + ks)*64 + lane ; holds W[nt*32+(lane&31)][ks*16+(lane>>5)*8 + j]
__global__ void k_wswz(const float* __restrict__ W, unsigned short* __restrict__ dst, int total) {
    int c = blockIdx.x * 256 + threadIdx.x;
    if (c >= total) return;
    int lane = c & 63;
    int ks = (c >> 6) % 24;
    int nt = c / (24 * 64);
    int n = nt * 32 + (lane & 31);
    int k0 = ks * 16 + ((lane >> 5) << 3);
    const float* src = &W[n * 384 + k0];
    unsigned short tmp[8];
#pragma unroll
    for (int j = 0; j < 8; ++j) tmp[j] = f2bf(src[j]);
    *(uint4*)&dst[(size_t)c * 8] = *(const uint4*)tmp;
}

// ------------------------------- main kernel -------------------------------
__global__ __launch_bounds__(256) void edge_main(
    const float* __restrict__ z, const unsigned short* __restrict__ xd,
    const unsigned short* __restrict__ W1s, const unsigned short* __restrict__ W2s,
    const unsigned short* __restrict__ Wos,
    const float* __restrict__ b1, const float* __restrict__ b2,
    const float* __restrict__ bo, const float* __restrict__ gamma,
    const float* __restrict__ beta, float* __restrict__ out)
{
    extern __shared__ char smem[];
    unsigned short* sA = (unsigned short*)smem;              // z_in / residual, 64*LPAD bf16
    unsigned short* sH = (unsigned short*)(smem + 64 * LPAD * 2);  // h1, 64*LPAD bf16
    float* sO = (float*)sH;                                  // overlaid: LN staging 64*OPAD f32

    const int tid = threadIdx.x;
    const int lane = tid & 63;
    const int w = tid >> 6;                   // wave 0..3
    const int i = blockIdx.x >> 3;            // 0..511
    const int j0 = (blockIdx.x & 7) << 6;     // 0..448

    // ---- stage z_in = [xd[i] | xd[j] | z[i,j,:]] as bf16 ----
    for (int c = tid; c < 64 * 16; c += 256) {
        int r = c >> 4, cc = (c & 15) << 3;
        *(uint4*)&sA[r * LPAD + cc] = *(const uint4*)&xd[i * 128 + cc];
        *(uint4*)&sA[r * LPAD + 128 + cc] = *(const uint4*)&xd[(j0 + r) * 128 + cc];
    }
    for (int c = tid; c < 64 * 32; c += 256) {
        int r = c >> 5, cc = (c & 31) << 2;
        float4 v = *(const float4*)&z[((size_t)((i << 9) + j0 + r) << 7) + cc];
        ushort4 o;
        o.x = f2bf(v.x); o.y = f2bf(v.y); o.z = f2bf(v.z); o.w = f2bf(v.w);
        *(ushort4*)&sA[r * LPAD + 256 + cc] = o;
    }
    __syncthreads();

    const int arow = lane & 31;
    const int kof = (lane >> 5) << 3;   // 0 or 8
    const int half2 = (lane >> 5) << 2; // 0 or 4 (C/D row offset)

    // ================= layer 1: h1 = relu(z_in @ W1^T + b1) =================
    {
        f32x16 acc[2][3] = {};
#pragma unroll 2
        for (int ks = 0; ks < 24; ++ks) {
            int k = ks * 16 + kof;
            bf16x8 a0 = *(const bf16x8*)&sA[arow * LPAD + k];
            bf16x8 a1 = *(const bf16x8*)&sA[(arow + 32) * LPAD + k];
#pragma unroll
            for (int t = 0; t < 3; ++t) {
                int nt = w * 3 + t;
                bf16x8 b = *(const bf16x8*)&W1s[(size_t)((nt * 24 + ks) * 64 + lane) * 8];
                acc[0][t] = __builtin_amdgcn_mfma_f32_32x32x16_bf16(a0, b, acc[0][t], 0, 0, 0);
                acc[1][t] = __builtin_amdgcn_mfma_f32_32x32x16_bf16(a1, b, acc[1][t], 0, 0, 0);
            }
        }
#pragma unroll
        for (int t = 0; t < 3; ++t) {
            int col = w * 96 + t * 32 + arow;
            float bias = b1[col];
#pragma unroll
            for (int mt = 0; mt < 2; ++mt) {
#pragma unroll
                for (int rg = 0; rg < 16; ++rg) {
                    int rr = mt * 32 + half2 + (rg & 3) + ((rg >> 2) << 3);
                    float v = acc[mt][t][rg] + bias;
                    v = v > 0.f ? v : 0.f;
                    sH[rr * LPAD + col] = f2bf(v);
                }
            }
        }
    }
    __syncthreads();

    // ========= layer 2: s = relu(h1 @ W2^T + b2) + z_in  (in place) =========
    {
        f32x16 acc[2][3] = {};
#pragma unroll 2
        for (int ks = 0; ks < 24; ++ks) {
            int k = ks * 16 + kof;
            bf16x8 a0 = *(const bf16x8*)&sH[arow * LPAD + k];
            bf16x8 a1 = *(const bf16x8*)&sH[(arow + 32) * LPAD + k];
#pragma unroll
            for (int t = 0; t < 3; ++t) {
                int nt = w * 3 + t;
                bf16x8 b = *(const bf16x8*)&W2s[(size_t)((nt * 24 + ks) * 64 + lane) * 8];
                acc[0][t] = __builtin_amdgcn_mfma_f32_32x32x16_bf16(a0, b, acc[0][t], 0, 0, 0);
                acc[1][t] = __builtin_amdgcn_mfma_f32_32x32x16_bf16(a1, b, acc[1][t], 0, 0, 0);
            }
        }
#pragma unroll
        for (int t = 0; t < 3; ++t) {
            int col = w * 96 + t * 32 + arow;
            float bias = b2[col];
#pragma unroll
            for (int mt = 0; mt < 2; ++mt) {
#pragma unroll
                for (int rg = 0; rg < 16; ++rg) {
                    int rr = mt * 32 + half2 + (rg & 3) + ((rg >> 2) << 3);
                    float v = acc[mt][t][rg] + bias;
                    v = v > 0.f ? v : 0.f;
                    float res = bf2f(sA[rr * LPAD + col]);
                    sA[rr * LPAD + col] = f2bf(v + res);
                }
            }
        }
    }
    __syncthreads();

    // ================= layer 3: out = s @ Wo^T + bo  (f32 in LDS) ===========
    {
        f32x16 acc[2] = {};
#pragma unroll 2
        for (int ks = 0; ks < 24; ++ks) {
            int k = ks * 16 + kof;
            bf16x8 a0 = *(const bf16x8*)&sA[arow * LPAD + k];
            bf16x8 a1 = *(const bf16x8*)&sA[(arow + 32) * LPAD + k];
            bf16x8 b = *(const bf16x8*)&Wos[(size_t)((w * 24 + ks) * 64 + lane) * 8];
            acc[0] = __builtin_amdgcn_mfma_f32_32x32x16_bf16(a0, b, acc[0], 0, 0, 0);
            acc[1] = __builtin_amdgcn_mfma_f32_32x32x16_bf16(a1, b, acc[1], 0, 0, 0);
        }
        int col = w * 32 + arow;
        float bias = bo[col];
#pragma unroll
        for (int mt = 0; mt < 2; ++mt) {
#pragma unroll
            for (int rg = 0; rg < 16; ++rg) {
                int rr = mt * 32 + half2 + (rg & 3) + ((rg >> 2) << 3);
                sO[rr * OPAD + col] = acc[mt][rg] + bias;
            }
        }
    }
    __syncthreads();

    // ============================ LayerNorm + store =========================
    {
        const int r = tid >> 2;       // row 0..63
        const int q = tid & 3;        // quarter
        float s = 0.f, ss = 0.f;
#pragma unroll
        for (int ii = 0; ii < 32; ++ii) {
            float v = sO[r * OPAD + q + (ii << 2)];   // interleaved: conflict-free
            s += v; ss += v * v;
        }
        s += __shfl_xor(s, 1);  ss += __shfl_xor(ss, 1);
        s += __shfl_xor(s, 2);  ss += __shfl_xor(ss, 2);
        const float mean = s * (1.f / 128.f);
        const float var = ss * (1.f / 128.f) - mean * mean;
        const float rstd = rsqrtf(var + 1e-5f);
        float* po = &out[((size_t)((i << 9) + j0 + r)) << 7];
#pragma unroll
        for (int ii = 0; ii < 8; ++ii) {
            int c0 = q * 32 + (ii << 2);
            float4 v = *(const float4*)&sO[r * OPAD + c0];
            float4 g = *(const float4*)&gamma[c0];
            float4 bb = *(const float4*)&beta[c0];
            float4 o;
            o.x = (v.x - mean) * rstd * g.x + bb.x;
            o.y = (v.y - mean) * rstd * g.y + bb.y;
            o.z = (v.z - mean) * rstd * g.z + bb.z;
            o.w = (v.w - mean) * rstd * g.w + bb.w;
            *(float4*)&po[c0] = o;
        }
    }
}

extern "C" void kernel_launch(void* const* d_in, const int* in_sizes, int n_in,
                              void* d_out, int out_size, void* d_ws, size_t ws_size,
                              hipStream_t stream) {
    const float* x     = (const float*)d_in[0];
    const float* z     = (const float*)d_in[1];
    const float* Wd    = (const float*)d_in[2];
    const float* bd    = (const float*)d_in[3];
    const float* W1    = (const float*)d_in[4];
    const float* b1    = (const float*)d_in[5];
    const float* W2    = (const float*)d_in[6];
    const float* b2    = (const float*)d_in[7];
    const float* Wo    = (const float*)d_in[8];
    const float* bo    = (const float*)d_in[9];
    const float* gamma = (const float*)d_in[10];
    const float* beta  = (const float*)d_in[11];
    float* out = (float*)d_out;

    unsigned short* xd  = (unsigned short*)d_ws;                       // 512*128*2   = 131072
    unsigned short* W1s = (unsigned short*)((char*)d_ws + 131072);     // 294912
    unsigned short* W2s = (unsigned short*)((char*)d_ws + 425984);     // 294912
    unsigned short* Wos = (unsigned short*)((char*)d_ws + 720896);     // 98304

    hipLaunchKernelGGL(k_xdown, dim3(64), dim3(128), 0, stream, x, Wd, bd, xd);
    hipLaunchKernelGGL(k_wswz, dim3(72), dim3(256), 0, stream, W1, W1s, 12 * 24 * 64);
    hipLaunchKernelGGL(k_wswz, dim3(72), dim3(256), 0, stream, W2, W2s, 12 * 24 * 64);
    hipLaunchKernelGGL(k_wswz, dim3(24), dim3(256), 0, stream, Wo, Wos, 4 * 24 * 64);

    const size_t smem = (size_t)(64 * LPAD * 2) * 2;   // sA + sH (sO overlaid) = 100352 B
    hipLaunchKernelGGL(edge_main, dim3(4096), dim3(256), smem, stream,
                       z, xd, W1s, W2s, Wos, b1, b2, bo, gamma, beta, out);
}

// Round 4
// 524.580 us; speedup vs baseline: 1.2384x; 1.2384x over previous
//
#include <hip/hip_runtime.h>

// ---------------------------------------------------------------------------
// EdgeUpdaterFrameDiff: x_down proj -> outer-concat edge bias -> 2-layer MLP
// with relu + residual -> out proj -> LayerNorm.  bf16 MFMA implementation.
//
// R4: R1-verbatim 64-row tile / grid / prep / LN (all HW-verified), but 768
// threads (12 waves) instead of 256 (4): each wave owns one 32-col N-tile
// (nt = w, col = nt*32+arow == R1's w*96+t*32+arow with t-loop collapsed).
// Theory: R1 was wave-starved (4 waves/CU, Occupancy 11.6%, MfmaUtil 15.5%);
// the 32-row restructure (R2/R3) fails non-deterministically, so raise
// occupancy via waves-per-block instead of blocks-per-CU.
// ---------------------------------------------------------------------------

using bf16x8 = __attribute__((ext_vector_type(8))) __bf16;
using f32x16 = __attribute__((ext_vector_type(16))) float;

#define LPAD 392            // bf16 row stride for 384-wide LDS tiles (16B aligned)
#define OPAD 132            // f32 row stride for 128-wide LN staging

__device__ inline unsigned short f2bf(float f) {
    union { float f; unsigned int u; } v; v.f = f;
    unsigned int r = v.u + 0x7fffu + ((v.u >> 16) & 1u);   // RNE
    return (unsigned short)(r >> 16);
}
__device__ inline float bf2f(unsigned short h) {
    union { unsigned int u; float f; } v; v.u = ((unsigned int)h) << 16;
    return v.f;
}

// ---------------- prep: x_down = x @ Wd^T + bd  (bf16 out) -----------------
// [R1 verbatim]
__global__ void k_xdown(const float* __restrict__ x, const float* __restrict__ Wd,
                        const float* __restrict__ bd, unsigned short* __restrict__ xd) {
    __shared__ float sx[8 * 256];
    const int t = threadIdx.x;           // 0..127 -> output col n
    const int ibase = blockIdx.x * 8;
    for (int c = t; c < 8 * 256; c += 128) sx[c] = x[ibase * 256 + c];
    __syncthreads();
    const float bias = bd[t];
    const float* wr = &Wd[t * 256];
    for (int ii = 0; ii < 8; ++ii) {
        const float* xr = &sx[ii * 256];
        float sum = 0.f;
#pragma unroll 8
        for (int k = 0; k < 256; k += 4) {
            float4 wv = *(const float4*)&wr[k];
            float4 xv = *(const float4*)&xr[k];
            sum += wv.x * xv.x + wv.y * xv.y + wv.z * xv.z + wv.w * xv.w;
        }
        xd[(ibase + ii) * 128 + t] = f2bf(sum + bias);
    }
}

// ------------- prep: swizzle weights into MFMA B-fragment order ------------
// [R1 verbatim]
__global__ void k_wswz(const float* __restrict__ W, unsigned short* __restrict__ dst, int total) {
    int c = blockIdx.x * 256 + threadIdx.x;
    if (c >= total) return;
    int lane = c & 63;
    int ks = (c >> 6) % 24;
    int nt = c / (24 * 64);
    int n = nt * 32 + (lane & 31);
    int k0 = ks * 16 + ((lane >> 5) << 3);
    const float* src = &W[n * 384 + k0];
    unsigned short tmp[8];
#pragma unroll
    for (int j = 0; j < 8; ++j) tmp[j] = f2bf(src[j]);
    *(uint4*)&dst[(size_t)c * 8] = *(const uint4*)tmp;
}

// ------------------------------- main kernel -------------------------------
__global__ __launch_bounds__(768) void edge_main(
    const float* __restrict__ z, const unsigned short* __restrict__ xd,
    const unsigned short* __restrict__ W1s, const unsigned short* __restrict__ W2s,
    const unsigned short* __restrict__ Wos,
    const float* __restrict__ b1, const float* __restrict__ b2,
    const float* __restrict__ bo, const float* __restrict__ gamma,
    const float* __restrict__ beta, float* __restrict__ out)
{
    extern __shared__ char smem[];
    unsigned short* sA = (unsigned short*)smem;                    // z_in / residual, 64*LPAD bf16
    unsigned short* sH = (unsigned short*)(smem + 64 * LPAD * 2);  // h1
    float* sO = (float*)sH;                                        // overlaid: LN staging 64*OPAD f32

    const int tid = threadIdx.x;
    const int lane = tid & 63;
    const int w = tid >> 6;                   // wave 0..11
    const int i = blockIdx.x >> 3;            // 0..511   [R1 decode]
    const int j0 = (blockIdx.x & 7) << 6;     // 0..448

    // ---- stage z_in = [xd[i] | xd[j] | z[i,j,:]] as bf16 ----  [R1 body, stride 768]
    for (int c = tid; c < 64 * 16; c += 768) {
        int r = c >> 4, cc = (c & 15) << 3;
        *(uint4*)&sA[r * LPAD + cc] = *(const uint4*)&xd[i * 128 + cc];
        *(uint4*)&sA[r * LPAD + 128 + cc] = *(const uint4*)&xd[(j0 + r) * 128 + cc];
    }
    for (int c = tid; c < 64 * 32; c += 768) {
        int r = c >> 5, cc = (c & 31) << 2;
        float4 v = *(const float4*)&z[((size_t)((i << 9) + j0 + r) << 7) + cc];
        ushort4 o;
        o.x = f2bf(v.x); o.y = f2bf(v.y); o.z = f2bf(v.z); o.w = f2bf(v.w);
        *(ushort4*)&sA[r * LPAD + 256 + cc] = o;
    }
    __syncthreads();

    const int arow = lane & 31;
    const int kof = (lane >> 5) << 3;   // 0 or 8
    const int half2 = (lane >> 5) << 2; // 0 or 4 (C/D row offset)

    // ===== layer 1: h1 = relu(z_in @ W1^T + b1); wave w -> N-tile nt=w =====
    {
        f32x16 acc0 = {}, acc1 = {};
#pragma unroll 2
        for (int ks = 0; ks < 24; ++ks) {
            int k = ks * 16 + kof;
            bf16x8 a0 = *(const bf16x8*)&sA[arow * LPAD + k];
            bf16x8 a1 = *(const bf16x8*)&sA[(arow + 32) * LPAD + k];
            bf16x8 b = *(const bf16x8*)&W1s[(size_t)((w * 24 + ks) * 64 + lane) * 8];
            acc0 = __builtin_amdgcn_mfma_f32_32x32x16_bf16(a0, b, acc0, 0, 0, 0);
            acc1 = __builtin_amdgcn_mfma_f32_32x32x16_bf16(a1, b, acc1, 0, 0, 0);
        }
        int col = w * 32 + arow;
        float bias = b1[col];
#pragma unroll
        for (int rg = 0; rg < 16; ++rg) {
            int rr = half2 + (rg & 3) + ((rg >> 2) << 3);
            float v0 = acc0[rg] + bias; v0 = v0 > 0.f ? v0 : 0.f;
            float v1 = acc1[rg] + bias; v1 = v1 > 0.f ? v1 : 0.f;
            sH[rr * LPAD + col] = f2bf(v0);
            sH[(rr + 32) * LPAD + col] = f2bf(v1);
        }
    }
    __syncthreads();

    // ===== layer 2: s = relu(h1 @ W2^T + b2) + z_in  (in place in sA) =====
    {
        f32x16 acc0 = {}, acc1 = {};
#pragma unroll 2
        for (int ks = 0; ks < 24; ++ks) {
            int k = ks * 16 + kof;
            bf16x8 a0 = *(const bf16x8*)&sH[arow * LPAD + k];
            bf16x8 a1 = *(const bf16x8*)&sH[(arow + 32) * LPAD + k];
            bf16x8 b = *(const bf16x8*)&W2s[(size_t)((w * 24 + ks) * 64 + lane) * 8];
            acc0 = __builtin_amdgcn_mfma_f32_32x32x16_bf16(a0, b, acc0, 0, 0, 0);
            acc1 = __builtin_amdgcn_mfma_f32_32x32x16_bf16(a1, b, acc1, 0, 0, 0);
        }
        int col = w * 32 + arow;
        float bias = b2[col];
#pragma unroll
        for (int rg = 0; rg < 16; ++rg) {
            int rr = half2 + (rg & 3) + ((rg >> 2) << 3);
            float v0 = acc0[rg] + bias; v0 = v0 > 0.f ? v0 : 0.f;
            float v1 = acc1[rg] + bias; v1 = v1 > 0.f ? v1 : 0.f;
            float r0 = bf2f(sA[rr * LPAD + col]);
            float r1 = bf2f(sA[(rr + 32) * LPAD + col]);
            sA[rr * LPAD + col] = f2bf(v0 + r0);
            sA[(rr + 32) * LPAD + col] = f2bf(v1 + r1);
        }
    }
    __syncthreads();

    // ===== layer 3: out = s @ Wo^T + bo; waves 0..7 -> (mt,nt) units =====
    if (w < 8) {
        const int mt3 = w >> 2;           // M-tile 0/1
        const int nt3 = w & 3;            // N-tile 0..3
        f32x16 acc = {};
#pragma unroll 2
        for (int ks = 0; ks < 24; ++ks) {
            int k = ks * 16 + kof;
            bf16x8 a0 = *(const bf16x8*)&sA[(arow + mt3 * 32) * LPAD + k];
            bf16x8 b = *(const bf16x8*)&Wos[(size_t)((nt3 * 24 + ks) * 64 + lane) * 8];
            acc = __builtin_amdgcn_mfma_f32_32x32x16_bf16(a0, b, acc, 0, 0, 0);
        }
        int col = nt3 * 32 + arow;
        float bias = bo[col];
#pragma unroll
        for (int rg = 0; rg < 16; ++rg) {
            int rr = mt3 * 32 + half2 + (rg & 3) + ((rg >> 2) << 3);
            sO[rr * OPAD + col] = acc[rg] + bias;
        }
    }
    __syncthreads();

    // ===================== LayerNorm + store  [R1 verbatim] =================
    if (tid < 256) {
        const int r = tid >> 2;       // row 0..63
        const int q = tid & 3;        // quarter
        float s = 0.f, ss = 0.f;
#pragma unroll
        for (int ii = 0; ii < 32; ++ii) {
            float v = sO[r * OPAD + q + (ii << 2)];
            s += v; ss += v * v;
        }
        s += __shfl_xor(s, 1);  ss += __shfl_xor(ss, 1);
        s += __shfl_xor(s, 2);  ss += __shfl_xor(ss, 2);
        const float mean = s * (1.f / 128.f);
        const float var = ss * (1.f / 128.f) - mean * mean;
        const float rstd = rsqrtf(var + 1e-5f);
        float* po = &out[((size_t)((i << 9) + j0 + r)) << 7];
#pragma unroll
        for (int ii = 0; ii < 8; ++ii) {
            int c0 = q * 32 + (ii << 2);
            float4 v = *(const float4*)&sO[r * OPAD + c0];
            float4 g = *(const float4*)&gamma[c0];
            float4 bb = *(const float4*)&beta[c0];
            float4 o;
            o.x = (v.x - mean) * rstd * g.x + bb.x;
            o.y = (v.y - mean) * rstd * g.y + bb.y;
            o.z = (v.z - mean) * rstd * g.z + bb.z;
            o.w = (v.w - mean) * rstd * g.w + bb.w;
            *(float4*)&po[c0] = o;
        }
    }
}

extern "C" void kernel_launch(void* const* d_in, const int* in_sizes, int n_in,
                              void* d_out, int out_size, void* d_ws, size_t ws_size,
                              hipStream_t stream) {
    const float* x     = (const float*)d_in[0];
    const float* z     = (const float*)d_in[1];
    const float* Wd    = (const float*)d_in[2];
    const float* bd    = (const float*)d_in[3];
    const float* W1    = (const float*)d_in[4];
    const float* b1    = (const float*)d_in[5];
    const float* W2    = (const float*)d_in[6];
    const float* b2    = (const float*)d_in[7];
    const float* Wo    = (const float*)d_in[8];
    const float* bo    = (const float*)d_in[9];
    const float* gamma = (const float*)d_in[10];
    const float* beta  = (const float*)d_in[11];
    float* out = (float*)d_out;

    unsigned short* xd  = (unsigned short*)d_ws;                       // 512*128*2   = 131072
    unsigned short* W1s = (unsigned short*)((char*)d_ws + 131072);     // 294912
    unsigned short* W2s = (unsigned short*)((char*)d_ws + 425984);     // 294912
    unsigned short* Wos = (unsigned short*)((char*)d_ws + 720896);     // 98304

    hipLaunchKernelGGL(k_xdown, dim3(64), dim3(128), 0, stream, x, Wd, bd, xd);
    hipLaunchKernelGGL(k_wswz, dim3(72), dim3(256), 0, stream, W1, W1s, 12 * 24 * 64);
    hipLaunchKernelGGL(k_wswz, dim3(72), dim3(256), 0, stream, W2, W2s, 12 * 24 * 64);
    hipLaunchKernelGGL(k_wswz, dim3(24), dim3(256), 0, stream, Wo, Wos, 4 * 24 * 64);

    const size_t smem = (size_t)(64 * LPAD * 2) * 2;   // sA + sH (sO overlaid) = 100352 B
    hipLaunchKernelGGL(edge_main, dim3(4096), dim3(768), smem, stream,
                       z, xd, W1s, W2s, Wos, b1, b2, bo, gamma, beta, out);
}